// Round 9
// baseline (547.242 us; speedup 1.0000x reference)
//
#include <hip/hip_runtime.h>
#include <math.h>

// Problem constants
#define T_DIM 16
#define B_DIM 128
#define N_DIM 2048
#define TB    (T_DIM * B_DIM)   // 2048 rows of the GEMM

// d_ws layout (bytes): h f32 16MB | psum 0.5MB | psum2 0.5MB | ssum 16KB
#define WS_H      0
#define WS_PSUM   16777216
#define WS_PSUM2  17301504
#define WS_SSUM   17825792

typedef __attribute__((ext_vector_type(8))) short short8;
typedef __attribute__((ext_vector_type(4))) float f32x4;

// bf16 split planes: [x0,x1,x2,W0,W1,W2], each [2048][2048] bf16 = 8MB.
// Static device global (module-load allocation; not hipMalloc -> graph-safe).
#define PLANE 4194304ull
__device__ __align__(16) unsigned short g_planes[6ull * PLANE];

// ---- probe helpers (asymmetric integer patterns, exact in bf16/f32) -------
__device__ __forceinline__ double probeA(int m, int k) {
    return (double)((m * 7 + k * 13) % 23 - 11);
}
__device__ __forceinline__ double probeB(int k, int n) {
    return (double)((k * 5 + n * 3) % 19 - 9);
}

// round-to-nearest-even f32 -> bf16; returns bits, writes back-converted f32
__device__ __forceinline__ unsigned bf16_rne(float f, float* back) {
    unsigned u = __float_as_uint(f);
    unsigned r = u + 0x7FFFu + ((u >> 16) & 1u);
    unsigned h = r >> 16;
    *back = __uint_as_float(h << 16);
    return h;
}

// ---- split kernel: f32 -> 3x bf16 planes for x and W, + exact ssum --------
// one block per source row (4096 rows total: x then W); thread = one k-octet.
__global__ __launch_bounds__(256)
void split_kernel(const float* __restrict__ x, const float* __restrict__ W,
                  double* __restrict__ ssum) {
    const int row = blockIdx.x;
    const int tid = threadIdx.x;
    const int mat = row >> 11;          // 0 = x, 1 = W
    const int r   = row & 2047;
    const float* src = (mat ? W : x) + (size_t)r * N_DIM;
    unsigned short* p0 = g_planes + (size_t)(3 * mat) * PLANE
                       + (size_t)r * N_DIM + tid * 8;

    float4 f0 = *(const float4*)(src + tid * 8);
    float4 f1 = *(const float4*)(src + tid * 8 + 4);
    float v[8] = {f0.x, f0.y, f0.z, f0.w, f1.x, f1.y, f1.z, f1.w};
    unsigned h0[8], h1[8], h2[8];
    double s = 0.0;
#pragma unroll
    for (int e = 0; e < 8; ++e) {
        float b;
        h0[e] = bf16_rne(v[e], &b); float r1 = v[e] - b;   // exact residuals
        h1[e] = bf16_rne(r1, &b);   float r2 = r1 - b;
        h2[e] = bf16_rne(r2, &b);
        s += (double)v[e];
    }
    uint4 u;
    u.x = h0[0] | (h0[1] << 16); u.y = h0[2] | (h0[3] << 16);
    u.z = h0[4] | (h0[5] << 16); u.w = h0[6] | (h0[7] << 16);
    *(uint4*)(p0) = u;
    u.x = h1[0] | (h1[1] << 16); u.y = h1[2] | (h1[3] << 16);
    u.z = h1[4] | (h1[5] << 16); u.w = h1[6] | (h1[7] << 16);
    *(uint4*)(p0 + PLANE) = u;
    u.x = h2[0] | (h2[1] << 16); u.y = h2[2] | (h2[3] << 16);
    u.z = h2[4] | (h2[5] << 16); u.w = h2[6] | (h2[7] << 16);
    *(uint4*)(p0 + 2 * PLANE) = u;

    if (mat == 0) {   // spatial row sum (exact f64, fixed order)
        for (int off = 32; off > 0; off >>= 1) s += __shfl_down(s, off, 64);
        __shared__ double wsum[4];
        int lane = tid & 63, wv = tid >> 6;
        if (lane == 0) wsum[wv] = s;
        __syncthreads();
        if (tid == 0) ssum[r] = (wsum[0] + wsum[1]) + (wsum[2] + wsum[3]);
    }
}

// ---- bf16 MFMA wiring probe ------------------------------------------------
// Validates the documented 16x16x32 layout (A: row=l&15, k=8*(l>>4)+j; B
// symmetric) against 8 hypotheses: arg-swap x 4 D-forms. Asymmetric integer
// data -> only the true wiring matches (exact compare). Failure -> fallback.
__device__ unsigned probe_bf16(float* crefF, int l) {
    int i0 = l >> 2, j0 = (l & 3) << 2;
    for (int jj = 0; jj < 4; ++jj) {
        double s = 0.0;
        for (int k = 0; k < 32; ++k) s += probeA(i0, k) * probeB(k, j0 + jj);
        crefF[i0 * 16 + j0 + jj] = (float)s;      // <= 3872, exact in f32
    }
    __syncthreads();
    short8 af, bf;
#pragma unroll
    for (int j = 0; j < 8; ++j) {
        int k = 8 * (l >> 4) + j;
        af[j] = (short)(__float_as_uint((float)probeA(l & 15, k)) >> 16);
        bf[j] = (short)(__float_as_uint((float)probeB(k, l & 15)) >> 16);
    }
    unsigned win = 0xFFFFFFFFu;
    for (int s = 0; s < 2; ++s) {
        f32x4 d = {0.f, 0.f, 0.f, 0.f};
        d = __builtin_amdgcn_mfma_f32_16x16x32_bf16(s ? bf : af, s ? af : bf,
                                                    d, 0, 0, 0);
        for (int dF = 0; dF < 4; ++dF) {
            float err = 0.f;
#pragma unroll
            for (int r = 0; r < 4; ++r) {
                int ii, jj;
                if (dF == 0)      { ii = 4 * (l >> 4) + r; jj = l & 15; }
                else if (dF == 1) { ii = (l >> 4) + 4 * r; jj = l & 15; }
                else if (dF == 2) { jj = 4 * (l >> 4) + r; ii = l & 15; }
                else              { jj = (l >> 4) + 4 * r; ii = l & 15; }
                err = fmaxf(err, fabsf(d[r] - crefF[ii * 16 + jj]));
            }
            for (int off = 1; off < 64; off <<= 1)
                err = fmaxf(err, __shfl_xor(err, off, 64));
            if (err < 0.5f && win == 0xFFFFFFFFu) win = (unsigned)(s * 4 + dF);
        }
    }
    return win;
}

// ---- GEMM h = x . W^T via 3-way bf16 split (6 MFMA products) ---------------
// v19: v18 numerics (validated absmax=0) + latency/locality fixes. R8 PMC:
// MfmaUtil 18.5 / VALUBusy 11 / Occ 20 -> latency-bound; FETCH 194MB @
// 1.0TB/s = 188us of the 232. Fixes:
//  (1) 4-way k-split (4 waves/block): 16 waves/CU (was 8), 2x loads in
//      flight. Epilogue: in-place scatter accumulation w1->w2->w3->w0
//      (4 barriers, zero extra registers -- no spill).
//  (2) XCD-aware 2D slab swizzle: xcd=bid&7 owns an 8x16 slab of the 32x32
//      block grid (bijective) -> A-band L2-resident, B-bands L2/L3-local.
#define MF(a, b, c) __builtin_amdgcn_mfma_f32_16x16x32_bf16((a), (b), (c), 0, 0, 0)

#define SIX_AB                                                        \
    accH[f][g] = MF(aa0, bb0[g], accH[f][g]);                         \
    accM[f][g] = MF(aa0, bb1[g], accM[f][g]);                         \
    accM[f][g] = MF(aa1, bb0[g], accM[f][g]);                         \
    accM[f][g] = MF(aa1, bb1[g], accM[f][g]);                         \
    accM[f][g] = MF(aa0, bb2[g], accM[f][g]);                         \
    accM[f][g] = MF(aa2, bb0[g], accM[f][g]);

#define SIX_BA                                                        \
    accH[f][g] = MF(bb0[g], aa0, accH[f][g]);                         \
    accM[f][g] = MF(bb1[g], aa0, accM[f][g]);                         \
    accM[f][g] = MF(bb0[g], aa1, accM[f][g]);                         \
    accM[f][g] = MF(bb1[g], aa1, accM[f][g]);                         \
    accM[f][g] = MF(bb2[g], aa0, accM[f][g]);                         \
    accM[f][g] = MF(bb0[g], aa2, accM[f][g]);

#define MAINLOOP(SIX)                                                 \
    for (int c = w; c < 64; c += 4) {                                 \
        const int koff = c * 32;                                      \
        short8 bb0[4], bb1[4], bb2[4];                                \
        _Pragma("unroll")                                             \
        for (int g = 0; g < 4; ++g) {                                 \
            const unsigned short* bp = Bbase + (size_t)(16 * g) * N_DIM + koff; \
            bb0[g] = *(const short8*)(bp);                            \
            bb1[g] = *(const short8*)(bp + PLANE);                    \
            bb2[g] = *(const short8*)(bp + 2 * PLANE);                \
        }                                                             \
        _Pragma("unroll")                                             \
        for (int f = 0; f < 4; ++f) {                                 \
            const unsigned short* ap = Abase + (size_t)(16 * f) * N_DIM + koff; \
            short8 aa0 = *(const short8*)(ap);                        \
            short8 aa1 = *(const short8*)(ap + PLANE);                \
            short8 aa2 = *(const short8*)(ap + 2 * PLANE);            \
            _Pragma("unroll")                                         \
            for (int g = 0; g < 4; ++g) { SIX }                       \
        }                                                             \
    }

// scatter-position loop over this wave's 64 accumulator elements
#define EPI(OP)                                                       \
    _Pragma("unroll")                                                 \
    for (int f = 0; f < 4; ++f)                                       \
        _Pragma("unroll")                                             \
        for (int g = 0; g < 4; ++g)                                   \
            _Pragma("unroll")                                         \
            for (int r = 0; r < 4; ++r) {                             \
                int ci = (16 * f + iD[r]) * 64 + 16 * g + jD[r];      \
                double sv = (double)accH[f][g][r] + (double)accM[f][g][r]; \
                OP;                                                   \
            }

__global__ __launch_bounds__(256, 3)
void gemm_bf16(const float* __restrict__ x, const float* __restrict__ W,
               float* __restrict__ C, double* __restrict__ psum,
               double* __restrict__ psum2) {
    __shared__ __align__(16) char smem[32768];   // probe Cref, then cbuf
    const int t    = threadIdx.x;
    const int lane = t & 63;
    const int w    = t >> 6;

    // XCD-aware slab swizzle: bid&7 = XCD; each XCD gets an 8x16 block slab.
    const int bid = blockIdx.y * 32 + blockIdx.x;
    const int xcd = bid & 7, ii = bid >> 3;
    const int bx = (xcd & 3) * 8 + (ii & 7);
    const int by = (xcd >> 2) * 16 + (ii >> 3);
    const int row0 = by * 64;
    const int col0 = bx * 64;
    const int band = by;

    const unsigned win = probe_bf16((float*)smem, lane);
    __syncthreads();
    double* cbuf = (double*)smem;                // 4096 doubles = 32KB

    if (win <= 7u) {
        const int swp = win >> 2, dF = win & 3;
        int iD[4], jD[4];
#pragma unroll
        for (int r = 0; r < 4; ++r) {
            if (dF == 0)      { iD[r] = 4 * (lane >> 4) + r; jD[r] = lane & 15; }
            else if (dF == 1) { iD[r] = (lane >> 4) + 4 * r; jD[r] = lane & 15; }
            else if (dF == 2) { jD[r] = 4 * (lane >> 4) + r; iD[r] = lane & 15; }
            else              { jD[r] = (lane >> 4) + 4 * r; iD[r] = lane & 15; }
        }

        const unsigned short* Abase =
            g_planes + (size_t)(row0 + (lane & 15)) * N_DIM + 8 * (lane >> 4);
        const unsigned short* Bbase =
            g_planes + 3 * PLANE + (size_t)(col0 + (lane & 15)) * N_DIM + 8 * (lane >> 4);

        f32x4 accH[4][4], accM[4][4];
#pragma unroll
        for (int f = 0; f < 4; ++f)
#pragma unroll
            for (int g = 0; g < 4; ++g) {
                accH[f][g] = (f32x4){0.f, 0.f, 0.f, 0.f};
                accM[f][g] = (f32x4){0.f, 0.f, 0.f, 0.f};
            }

        if (!swp) { MAINLOOP(SIX_AB) } else { MAINLOOP(SIX_BA) }

        // 4-wave combine: in-place accumulation at scatter position (all
        // waves share the identical lane->(i,j) map).
        __syncthreads();
        if (w == 1) { EPI(cbuf[ci] = sv) }
        __syncthreads();
        if (w == 2) { EPI(cbuf[ci] += sv) }
        __syncthreads();
        if (w == 3) { EPI(cbuf[ci] += sv) }
        __syncthreads();
        if (w == 0) {
            EPI(
                double vv = cbuf[ci] + sv;
                cbuf[ci] = vv;
                C[(size_t)(row0 + 16 * f + iD[r]) * N_DIM
                  + col0 + 16 * g + jD[r]] = (float)vv
            )
            // column stats over the 64x64 tile (same-wave DS ordering)
            double s = 0.0, q = 0.0;
#pragma unroll
            for (int r = 0; r < 64; ++r) {
                double v = cbuf[r * 64 + lane];
                s += v;
                q = fma(v, v, q);
            }
            psum [band * N_DIM + col0 + lane] = s;
            psum2[band * N_DIM + col0 + lane] = q;
        }
    } else {
        // correctness-only fallback (probe failed): naive f64 dot products
        for (int off = t; off < 64 * 64; off += 256) {
            int rr = off >> 6, cc = off & 63;
            const float* xr = x + (size_t)(row0 + rr) * N_DIM;
            const float* wr = W + (size_t)(col0 + cc) * N_DIM;
            double s = 0.0;
            for (int k = 0; k < N_DIM; ++k)
                s += (double)xr[k] * (double)wr[k];
            C[(size_t)(row0 + rr) * N_DIM + col0 + cc] = (float)s;
        }
        __syncthreads();
        if (t < 64) {
            double s = 0.0, q = 0.0;
            for (int rr = 0; rr < 64; ++rr) {
                double v = (double)C[(size_t)(row0 + rr) * N_DIM + col0 + t];
                s += v;
                q = fma(v, v, q);
            }
            psum [band * N_DIM + col0 + t] = s;
            psum2[band * N_DIM + col0 + t] = q;
        }
    }
}

// ---- fused BN-final + BN-apply + temporal-sum + triple LIF + output -------
__global__ __launch_bounds__(256)
void fused_lif_kernel(const float* __restrict__ x, const float* __restrict__ h,
                      const double* __restrict__ psum, const double* __restrict__ psum2,
                      const float* __restrict__ gamma, const float* __restrict__ beta,
                      const double* __restrict__ ssum, float* __restrict__ out) {
    int idx = blockIdx.x * 256 + threadIdx.x;
    int n = idx & (N_DIM - 1);
    int b = idx >> 11;
    // BN scale/shift for this column
    double s = 0.0, s2 = 0.0;
#pragma unroll
    for (int c = 0; c < 32; ++c) {
        s  += psum [c * N_DIM + n];
        s2 += psum2[c * N_DIM + n];
    }
    double mean = s * (1.0 / 2048.0);
    double var  = s2 * (1.0 / 2048.0) - mean * mean;
    double istd = 1.0 / sqrt(var + 1e-5);
    double sc = istd * (double)gamma[n];
    double sh = (double)beta[n] - mean * sc;
    // temporal sum (ascending t, f64)
    float xv[T_DIM];
    double ts = 0.0;
#pragma unroll
    for (int t = 0; t < T_DIM; ++t) {
        xv[t] = x[(size_t)(t * B_DIM + b) * N_DIM + n];
        ts += (double)xv[t];
    }
    double v1 = 0.0, v2 = 0.0, v3 = 0.0;
#pragma unroll
    for (int t = 0; t < T_DIM; ++t) {
        size_t off = (size_t)(t * B_DIM + b) * N_DIM + n;
        double hv = fma((double)h[off], sc, sh);
        v1 = v1 * 0.5 + hv;
        bool s1 = (v1 >= 1.0); if (s1) v1 = 0.0;
        double in2 = s1 ? ssum[t * B_DIM + b] : 0.0;
        v2 = v2 * 0.5 + in2;
        bool s2b = (v2 >= 1.0); if (s2b) v2 = 0.0;
        double in3 = s1 ? ts : 0.0;
        v3 = v3 * 0.5 + in3;
        bool s3 = (v3 >= 1.0); if (s3) v3 = 0.0;
        out[off] = xv[t] + ((s2b && s3) ? 1.0f : 0.0f);
    }
}

extern "C" void kernel_launch(void* const* d_in, const int* in_sizes, int n_in,
                              void* d_out, int out_size, void* d_ws, size_t ws_size,
                              hipStream_t stream) {
    const float* x     = (const float*)d_in[0];   // [16,128,2048]
    const float* W     = (const float*)d_in[1];   // [2048,2048]
    const float* gamma = (const float*)d_in[2];   // [2048]
    const float* beta  = (const float*)d_in[3];   // [2048]
    float* out = (float*)d_out;

    char* ws = (char*)d_ws;
    float*  h     = (float*)(ws + WS_H);
    double* psum  = (double*)(ws + WS_PSUM);
    double* psum2 = (double*)(ws + WS_PSUM2);
    double* ssum  = (double*)(ws + WS_SSUM);

    split_kernel<<<4096, 256, 0, stream>>>(x, W, ssum);
    gemm_bf16<<<dim3(N_DIM / 64, TB / 64), 256, 0, stream>>>(x, W, h, psum, psum2);
    fused_lif_kernel<<<(B_DIM * N_DIM) / 256, 256, 0, stream>>>(
        x, h, psum, psum2, gamma, beta, ssum, out);
}

// Round 10
// 292.962 us; speedup vs baseline: 1.8680x; 1.8680x over previous
//
#include <hip/hip_runtime.h>
#include <math.h>

// Problem constants
#define T_DIM 16
#define B_DIM 128
#define N_DIM 2048
#define TB    (T_DIM * B_DIM)   // 2048 rows of the GEMM

// d_ws layout (bytes): h f32 16MB | psum 0.5MB | psum2 0.5MB | ssum 16KB
#define WS_H      0
#define WS_PSUM   16777216
#define WS_PSUM2  17301504
#define WS_SSUM   17825792

typedef __attribute__((ext_vector_type(8))) short short8;
typedef __attribute__((ext_vector_type(4))) float f32x4;

// bf16 split planes: [x0,x1,x2,W0,W1,W2], each [2048][2048] bf16 = 8MB.
// Static device global (module-load allocation; not hipMalloc -> graph-safe).
#define PLANE 4194304ull
__device__ __align__(16) unsigned short g_planes[6ull * PLANE];

// ---- probe helpers (asymmetric integer patterns, exact in bf16/f32) -------
__device__ __forceinline__ double probeA(int m, int k) {
    return (double)((m * 7 + k * 13) % 23 - 11);
}
__device__ __forceinline__ double probeB(int k, int n) {
    return (double)((k * 5 + n * 3) % 19 - 9);
}

// round-to-nearest-even f32 -> bf16; returns bits, writes back-converted f32
__device__ __forceinline__ unsigned bf16_rne(float f, float* back) {
    unsigned u = __float_as_uint(f);
    unsigned r = u + 0x7FFFu + ((u >> 16) & 1u);
    unsigned h = r >> 16;
    *back = __uint_as_float(h << 16);
    return h;
}

// ---- split kernel: f32 -> 3x bf16 planes for x and W, + exact ssum --------
// one block per source row (4096 rows total: x then W); thread = one k-octet.
__global__ __launch_bounds__(256)
void split_kernel(const float* __restrict__ x, const float* __restrict__ W,
                  double* __restrict__ ssum) {
    const int row = blockIdx.x;
    const int tid = threadIdx.x;
    const int mat = row >> 11;          // 0 = x, 1 = W
    const int r   = row & 2047;
    const float* src = (mat ? W : x) + (size_t)r * N_DIM;
    unsigned short* p0 = g_planes + (size_t)(3 * mat) * PLANE
                       + (size_t)r * N_DIM + tid * 8;

    float4 f0 = *(const float4*)(src + tid * 8);
    float4 f1 = *(const float4*)(src + tid * 8 + 4);
    float v[8] = {f0.x, f0.y, f0.z, f0.w, f1.x, f1.y, f1.z, f1.w};
    unsigned h0[8], h1[8], h2[8];
    double s = 0.0;
#pragma unroll
    for (int e = 0; e < 8; ++e) {
        float b;
        h0[e] = bf16_rne(v[e], &b); float r1 = v[e] - b;   // exact residuals
        h1[e] = bf16_rne(r1, &b);   float r2 = r1 - b;
        h2[e] = bf16_rne(r2, &b);
        s += (double)v[e];
    }
    uint4 u;
    u.x = h0[0] | (h0[1] << 16); u.y = h0[2] | (h0[3] << 16);
    u.z = h0[4] | (h0[5] << 16); u.w = h0[6] | (h0[7] << 16);
    *(uint4*)(p0) = u;
    u.x = h1[0] | (h1[1] << 16); u.y = h1[2] | (h1[3] << 16);
    u.z = h1[4] | (h1[5] << 16); u.w = h1[6] | (h1[7] << 16);
    *(uint4*)(p0 + PLANE) = u;
    u.x = h2[0] | (h2[1] << 16); u.y = h2[2] | (h2[3] << 16);
    u.z = h2[4] | (h2[5] << 16); u.w = h2[6] | (h2[7] << 16);
    *(uint4*)(p0 + 2 * PLANE) = u;

    if (mat == 0) {   // spatial row sum (exact f64, fixed order)
        for (int off = 32; off > 0; off >>= 1) s += __shfl_down(s, off, 64);
        __shared__ double wsum[4];
        int lane = tid & 63, wv = tid >> 6;
        if (lane == 0) wsum[wv] = s;
        __syncthreads();
        if (tid == 0) ssum[r] = (wsum[0] + wsum[1]) + (wsum[2] + wsum[3]);
    }
}

// ---- bf16 MFMA wiring probe ------------------------------------------------
// Validates the documented 16x16x32 layout (A: row=l&15, k=8*(l>>4)+j; B
// symmetric) against 8 hypotheses: arg-swap x 4 D-forms. Asymmetric integer
// data -> only the true wiring matches (exact compare). Failure -> fallback.
__device__ unsigned probe_bf16(float* crefF, int l) {
    int i0 = l >> 2, j0 = (l & 3) << 2;
    for (int jj = 0; jj < 4; ++jj) {
        double s = 0.0;
        for (int k = 0; k < 32; ++k) s += probeA(i0, k) * probeB(k, j0 + jj);
        crefF[i0 * 16 + j0 + jj] = (float)s;      // <= 3872, exact in f32
    }
    __syncthreads();
    short8 af, bf;
#pragma unroll
    for (int j = 0; j < 8; ++j) {
        int k = 8 * (l >> 4) + j;
        af[j] = (short)(__float_as_uint((float)probeA(l & 15, k)) >> 16);
        bf[j] = (short)(__float_as_uint((float)probeB(k, l & 15)) >> 16);
    }
    unsigned win = 0xFFFFFFFFu;
    for (int s = 0; s < 2; ++s) {
        f32x4 d = {0.f, 0.f, 0.f, 0.f};
        d = __builtin_amdgcn_mfma_f32_16x16x32_bf16(s ? bf : af, s ? af : bf,
                                                    d, 0, 0, 0);
        for (int dF = 0; dF < 4; ++dF) {
            float err = 0.f;
#pragma unroll
            for (int r = 0; r < 4; ++r) {
                int ii, jj;
                if (dF == 0)      { ii = 4 * (l >> 4) + r; jj = l & 15; }
                else if (dF == 1) { ii = (l >> 4) + 4 * r; jj = l & 15; }
                else if (dF == 2) { jj = 4 * (l >> 4) + r; ii = l & 15; }
                else              { jj = (l >> 4) + 4 * r; ii = l & 15; }
                err = fmaxf(err, fabsf(d[r] - crefF[ii * 16 + jj]));
            }
            for (int off = 1; off < 64; off <<= 1)
                err = fmaxf(err, __shfl_xor(err, off, 64));
            if (err < 0.5f && win == 0xFFFFFFFFu) win = (unsigned)(s * 4 + dF);
        }
    }
    return win;
}

// ---- GEMM h = x . W^T via 3-way bf16 split (6 MFMA products) ---------------
// v20: R8's proven shell (128 thr, 2-wave k-split, launch_bounds(128,2))
// with two mechanism-independent fixes. R9 lesson (3rd spill round): the
// schedule's register budget is THE constraint -- launch_bounds(256,3)
// capped regs below the accumulator size -> 627MB scratch.
//  (1) merged accumulator: all 6 split products accumulate into ONE
//      acc[4][4] (64 AGPRs, was 128). MFMA rounds C+AB to f32 every step
//      already; folding the O(2^-8) M-terms in adds rounding of the same
//      class (validated absmax=0 twice). Frees 64 regs -> the ~36 chunk
//      loads can all stay in flight (R8's MfmaUtil 18.5% = load batching
//      serialized by reg starvation).
//  (2) XCD slab swizzle (bijective): xcd=bid&7 owns an 8x16 slab of the
//      32x32 grid -> A-band L2-resident, B-slab L3-resident -> fragment
//      load latency ~900 -> ~200-450 cy.
// Counter attribution: FETCH drop = (2); MfmaUtil rise beyond it = (1).
#define MF(a, b, c) __builtin_amdgcn_mfma_f32_16x16x32_bf16((a), (b), (c), 0, 0, 0)

#define SIX_AB                                                        \
    acc[f][g] = MF(aa0, bb0[g], acc[f][g]);                           \
    acc[f][g] = MF(aa0, bb1[g], acc[f][g]);                           \
    acc[f][g] = MF(aa1, bb0[g], acc[f][g]);                           \
    acc[f][g] = MF(aa1, bb1[g], acc[f][g]);                           \
    acc[f][g] = MF(aa0, bb2[g], acc[f][g]);                           \
    acc[f][g] = MF(aa2, bb0[g], acc[f][g]);

#define SIX_BA                                                        \
    acc[f][g] = MF(bb0[g], aa0, acc[f][g]);                           \
    acc[f][g] = MF(bb1[g], aa0, acc[f][g]);                           \
    acc[f][g] = MF(bb0[g], aa1, acc[f][g]);                           \
    acc[f][g] = MF(bb1[g], aa1, acc[f][g]);                           \
    acc[f][g] = MF(bb2[g], aa0, acc[f][g]);                           \
    acc[f][g] = MF(bb0[g], aa2, acc[f][g]);

#define MAINLOOP(SIX)                                                 \
    for (int c = w; c < 64; c += 2) {                                 \
        const int koff = c * 32;                                      \
        short8 bb0[4], bb1[4], bb2[4];                                \
        _Pragma("unroll")                                             \
        for (int g = 0; g < 4; ++g) {                                 \
            const unsigned short* bp = Bbase + (size_t)(16 * g) * N_DIM + koff; \
            bb0[g] = *(const short8*)(bp);                            \
            bb1[g] = *(const short8*)(bp + PLANE);                    \
            bb2[g] = *(const short8*)(bp + 2 * PLANE);                \
        }                                                             \
        _Pragma("unroll")                                             \
        for (int f = 0; f < 4; ++f) {                                 \
            const unsigned short* ap = Abase + (size_t)(16 * f) * N_DIM + koff; \
            short8 aa0 = *(const short8*)(ap);                        \
            short8 aa1 = *(const short8*)(ap + PLANE);                \
            short8 aa2 = *(const short8*)(ap + 2 * PLANE);            \
            _Pragma("unroll")                                         \
            for (int g = 0; g < 4; ++g) { SIX }                       \
        }                                                             \
    }

// scatter-position loop over this wave's 64 accumulator elements
#define EPI(OP)                                                       \
    _Pragma("unroll")                                                 \
    for (int f = 0; f < 4; ++f)                                       \
        _Pragma("unroll")                                             \
        for (int g = 0; g < 4; ++g)                                   \
            _Pragma("unroll")                                         \
            for (int r = 0; r < 4; ++r) {                             \
                int ci = (16 * f + iD[r]) * 64 + 16 * g + jD[r];      \
                double sv = (double)acc[f][g][r];                     \
                OP;                                                   \
            }

__global__ __launch_bounds__(128, 2)
void gemm_bf16(const float* __restrict__ x, const float* __restrict__ W,
               float* __restrict__ C, double* __restrict__ psum,
               double* __restrict__ psum2) {
    __shared__ __align__(16) char smem[32768];   // probe Cref, then cbuf
    const int t    = threadIdx.x;
    const int lane = t & 63;
    const int w    = t >> 6;

    // XCD-aware slab swizzle: bid&7 = XCD; each XCD gets an 8x16 block slab.
    const int bid = blockIdx.y * 32 + blockIdx.x;
    const int xcd = bid & 7, ii = bid >> 3;
    const int bx = (xcd & 3) * 8 + (ii & 7);
    const int by = (xcd >> 2) * 16 + (ii >> 3);
    const int row0 = by * 64;
    const int col0 = bx * 64;
    const int band = by;

    const unsigned win = probe_bf16((float*)smem, lane);
    __syncthreads();
    double* cbuf = (double*)smem;                // 4096 doubles = 32KB

    if (win <= 7u) {
        const int swp = win >> 2, dF = win & 3;
        int iD[4], jD[4];
#pragma unroll
        for (int r = 0; r < 4; ++r) {
            if (dF == 0)      { iD[r] = 4 * (lane >> 4) + r; jD[r] = lane & 15; }
            else if (dF == 1) { iD[r] = (lane >> 4) + 4 * r; jD[r] = lane & 15; }
            else if (dF == 2) { jD[r] = 4 * (lane >> 4) + r; iD[r] = lane & 15; }
            else              { jD[r] = (lane >> 4) + 4 * r; iD[r] = lane & 15; }
        }

        const unsigned short* Abase =
            g_planes + (size_t)(row0 + (lane & 15)) * N_DIM + 8 * (lane >> 4);
        const unsigned short* Bbase =
            g_planes + 3 * PLANE + (size_t)(col0 + (lane & 15)) * N_DIM + 8 * (lane >> 4);

        f32x4 acc[4][4];
#pragma unroll
        for (int f = 0; f < 4; ++f)
#pragma unroll
            for (int g = 0; g < 4; ++g)
                acc[f][g] = (f32x4){0.f, 0.f, 0.f, 0.f};

        if (!swp) { MAINLOOP(SIX_AB) } else { MAINLOOP(SIX_BA) }

        // 2-wave combine: in-place accumulation at scatter position (both
        // waves share the identical lane->(i,j) map).
        __syncthreads();
        if (w == 1) { EPI(cbuf[ci] = sv) }
        __syncthreads();
        if (w == 0) {
            EPI(
                double vv = cbuf[ci] + sv;
                cbuf[ci] = vv;
                C[(size_t)(row0 + 16 * f + iD[r]) * N_DIM
                  + col0 + 16 * g + jD[r]] = (float)vv
            )
            // column stats over the 64x64 tile (same-wave DS ordering)
            double s = 0.0, q = 0.0;
#pragma unroll
            for (int r = 0; r < 64; ++r) {
                double v = cbuf[r * 64 + lane];
                s += v;
                q = fma(v, v, q);
            }
            psum [band * N_DIM + col0 + lane] = s;
            psum2[band * N_DIM + col0 + lane] = q;
        }
    } else {
        // correctness-only fallback (probe failed): naive f64 dot products
        for (int off = t; off < 64 * 64; off += 128) {
            int rr = off >> 6, cc = off & 63;
            const float* xr = x + (size_t)(row0 + rr) * N_DIM;
            const float* wr = W + (size_t)(col0 + cc) * N_DIM;
            double s = 0.0;
            for (int k = 0; k < N_DIM; ++k)
                s += (double)xr[k] * (double)wr[k];
            C[(size_t)(row0 + rr) * N_DIM + col0 + cc] = (float)s;
        }
        __syncthreads();
        if (t < 64) {
            double s = 0.0, q = 0.0;
            for (int rr = 0; rr < 64; ++rr) {
                double v = (double)C[(size_t)(row0 + rr) * N_DIM + col0 + t];
                s += v;
                q = fma(v, v, q);
            }
            psum [band * N_DIM + col0 + t] = s;
            psum2[band * N_DIM + col0 + t] = q;
        }
    }
}

// ---- fused BN-final + BN-apply + temporal-sum + triple LIF + output -------
__global__ __launch_bounds__(256)
void fused_lif_kernel(const float* __restrict__ x, const float* __restrict__ h,
                      const double* __restrict__ psum, const double* __restrict__ psum2,
                      const float* __restrict__ gamma, const float* __restrict__ beta,
                      const double* __restrict__ ssum, float* __restrict__ out) {
    int idx = blockIdx.x * 256 + threadIdx.x;
    int n = idx & (N_DIM - 1);
    int b = idx >> 11;
    // BN scale/shift for this column
    double s = 0.0, s2 = 0.0;
#pragma unroll
    for (int c = 0; c < 32; ++c) {
        s  += psum [c * N_DIM + n];
        s2 += psum2[c * N_DIM + n];
    }
    double mean = s * (1.0 / 2048.0);
    double var  = s2 * (1.0 / 2048.0) - mean * mean;
    double istd = 1.0 / sqrt(var + 1e-5);
    double sc = istd * (double)gamma[n];
    double sh = (double)beta[n] - mean * sc;
    // temporal sum (ascending t, f64)
    float xv[T_DIM];
    double ts = 0.0;
#pragma unroll
    for (int t = 0; t < T_DIM; ++t) {
        xv[t] = x[(size_t)(t * B_DIM + b) * N_DIM + n];
        ts += (double)xv[t];
    }
    double v1 = 0.0, v2 = 0.0, v3 = 0.0;
#pragma unroll
    for (int t = 0; t < T_DIM; ++t) {
        size_t off = (size_t)(t * B_DIM + b) * N_DIM + n;
        double hv = fma((double)h[off], sc, sh);
        v1 = v1 * 0.5 + hv;
        bool s1 = (v1 >= 1.0); if (s1) v1 = 0.0;
        double in2 = s1 ? ssum[t * B_DIM + b] : 0.0;
        v2 = v2 * 0.5 + in2;
        bool s2b = (v2 >= 1.0); if (s2b) v2 = 0.0;
        double in3 = s1 ? ts : 0.0;
        v3 = v3 * 0.5 + in3;
        bool s3 = (v3 >= 1.0); if (s3) v3 = 0.0;
        out[off] = xv[t] + ((s2b && s3) ? 1.0f : 0.0f);
    }
}

extern "C" void kernel_launch(void* const* d_in, const int* in_sizes, int n_in,
                              void* d_out, int out_size, void* d_ws, size_t ws_size,
                              hipStream_t stream) {
    const float* x     = (const float*)d_in[0];   // [16,128,2048]
    const float* W     = (const float*)d_in[1];   // [2048,2048]
    const float* gamma = (const float*)d_in[2];   // [2048]
    const float* beta  = (const float*)d_in[3];   // [2048]
    float* out = (float*)d_out;

    char* ws = (char*)d_ws;
    float*  h     = (float*)(ws + WS_H);
    double* psum  = (double*)(ws + WS_PSUM);
    double* psum2 = (double*)(ws + WS_PSUM2);
    double* ssum  = (double*)(ws + WS_SSUM);

    split_kernel<<<4096, 256, 0, stream>>>(x, W, ssum);
    gemm_bf16<<<dim3(32, 32), 128, 0, stream>>>(x, W, h, psum, psum2);
    fused_lif_kernel<<<(B_DIM * N_DIM) / 256, 256, 0, stream>>>(
        x, h, psum, psum2, gamma, beta, ssum, out);
}